// Round 13
// baseline (502.307 us; speedup 1.0000x reference)
//
#include <hip/hip_runtime.h>
#include <hip/hip_bf16.h>

typedef __hip_bfloat16 bf16;
typedef __attribute__((ext_vector_type(8))) short short8;
typedef __attribute__((ext_vector_type(4))) float f32x4;

#define DEVINL __device__ __forceinline__

// async global->LDS, 16B per lane. LDS dest must be wave-uniform base; HW adds lane*16.
DEVINL void gload_lds16(const void* g, void* lds) {
  __builtin_amdgcn_global_load_lds(
      (const __attribute__((address_space(1))) unsigned int*)g,
      (__attribute__((address_space(3))) unsigned int*)lds,
      16, 0, 0);
}

// XCD-aware chunked swizzle (T1). fid = physical flat block id; returns logical id.
// Requires nwg % 8 == 0 for bijectivity; falls back to identity otherwise.
DEVINL int xcd_swizzle(int fid, int nwg) {
  if (nwg & 7) return fid;
  return (fid & 7) * (nwg >> 3) + (fid >> 3);
}

// ---------------- prep kernels ----------------

__global__ void k_convert_bf16(const float* __restrict__ in, bf16* __restrict__ out, int n) {
  int i = (blockIdx.x * blockDim.x + threadIdx.x) * 4;
  if (i + 3 < n) {
    float4 v = *(const float4*)(in + i);
    out[i + 0] = __float2bfloat16(v.x);
    out[i + 1] = __float2bfloat16(v.y);
    out[i + 2] = __float2bfloat16(v.z);
    out[i + 3] = __float2bfloat16(v.w);
  }
}

// out[b][c][r] = in[b][r][c], f32 -> bf16. R,C multiples of 32.
__global__ void k_transpose_to_bf16(const float* __restrict__ in, bf16* __restrict__ out,
                                    int R, int C, long long in_bstride, long long out_bstride) {
  __shared__ float tile[32][33];
  in  += (long long)blockIdx.z * in_bstride;
  out += (long long)blockIdx.z * out_bstride;
  int c0 = blockIdx.x * 32, r0 = blockIdx.y * 32;
  int tx = threadIdx.x, ty = threadIdx.y;  // 32x8
  #pragma unroll
  for (int i = ty; i < 32; i += 8)
    tile[i][tx] = in[(long long)(r0 + i) * C + c0 + tx];
  __syncthreads();
  #pragma unroll
  for (int i = ty; i < 32; i += 8)
    out[(long long)(c0 + i) * R + r0 + tx] = __float2bfloat16(tile[tx][i]);
}

// build gating bias vector (640) and zero pad rows 576..639 of Wgt
__global__ void k_pack_misc(const float* __restrict__ gb1, const float* __restrict__ lb1,
                            float* __restrict__ gbias, bf16* __restrict__ Wgt) {
  int i = blockIdx.x * blockDim.x + threadIdx.x;
  if (i < 640) {
    float v;
    if (i < 512) v = gb1[i];            // (D,G) flat: d*64+g
    else if (i < 576) v = lb1[i - 512]; // lb1[g]
    else v = 0.f;
    gbias[i] = v;
  }
  if (i < 64 * 1024) Wgt[576 * 1024 + i] = __float2bfloat16(0.f);
}

// ---------------- main GEMM: C = act(A @ Bt^T + bias) ----------------
// 128x128 tile, BK=64, 256 threads (4 waves, each 64x64 out). XCD-swizzled.
template <bool RELU>
__global__ __launch_bounds__(256, 2) void k_gemm_bt(
    const bf16* __restrict__ A, long long a_bstride, int lda,
    const bf16* __restrict__ Bt, long long b_bstride,
    const float* __restrict__ bias, long long bias_bstride,
    bf16* __restrict__ C, long long c_bstride,
    int N, int K) {
  __shared__ __align__(16) short sA[128 * 64];
  __shared__ __align__(16) short sB[128 * 64];

  const int tid = threadIdx.x;
  const int wave = tid >> 6, lane = tid & 63;

  // XCD-aware block remap (keeps n fastest so A-sharing blocks stay on one XCD)
  const int nwg = gridDim.x * gridDim.y * gridDim.z;
  int fid = blockIdx.x + gridDim.x * (blockIdx.y + gridDim.y * blockIdx.z);
  int nid = xcd_swizzle(fid, nwg);
  const int bx = nid % gridDim.x;  nid /= gridDim.x;
  const int by = nid % gridDim.y;
  const int e  = nid / gridDim.y;
  const int m0 = by * 128, n0 = bx * 128;

  A    += (long long)e * a_bstride;
  Bt   += (long long)e * b_bstride;
  bias += (long long)e * bias_bstride;
  C    += (long long)e * c_bstride;

  const int wm = (wave >> 1) * 64, wn = (wave & 1) * 64;

  f32x4 acc[4][4];
  #pragma unroll
  for (int m = 0; m < 4; ++m)
    #pragma unroll
    for (int n = 0; n < 4; ++n)
      acc[m][n] = (f32x4){0.f, 0.f, 0.f, 0.f};

  const int KT = K >> 6;
  for (int kt = 0; kt < KT; ++kt) {
    const int k0 = kt << 6;
    #pragma unroll
    for (int c = 0; c < 4; ++c) {
      int i = c * 256 + tid;
      int r = i >> 3, col = (i & 7) * 8;
      gload_lds16(A + (size_t)(m0 + r) * lda + k0 + col,
                  (char*)sA + (c * 256 + wave * 64) * 16);
    }
    #pragma unroll
    for (int c = 0; c < 4; ++c) {
      int i = c * 256 + tid;
      int r = i >> 3, col = (i & 7) * 8;
      gload_lds16(Bt + (size_t)(n0 + r) * K + k0 + col,
                  (char*)sB + (c * 256 + wave * 64) * 16);
    }
    __syncthreads();

    #pragma unroll
    for (int ks = 0; ks < 2; ++ks) {
      const int kb = ks * 32 + (lane >> 4) * 8;
      short8 af[4], bfr[4];
      #pragma unroll
      for (int m = 0; m < 4; ++m)
        af[m] = *(const short8*)&sA[(wm + m * 16 + (lane & 15)) * 64 + kb];
      #pragma unroll
      for (int n = 0; n < 4; ++n)
        bfr[n] = *(const short8*)&sB[(wn + n * 16 + (lane & 15)) * 64 + kb];
      #pragma unroll
      for (int m = 0; m < 4; ++m)
        #pragma unroll
        for (int n = 0; n < 4; ++n)
          acc[m][n] = __builtin_amdgcn_mfma_f32_16x16x32_bf16(af[m], bfr[n], acc[m][n], 0, 0, 0);
    }
    __syncthreads();
  }

  // epilogue: C/D layout col=lane&15, row=(lane>>4)*4+j
  #pragma unroll
  for (int m = 0; m < 4; ++m) {
    #pragma unroll
    for (int n = 0; n < 4; ++n) {
      #pragma unroll
      for (int j = 0; j < 4; ++j) {
        int row = m0 + wm + m * 16 + (lane >> 4) * 4 + j;
        int col = n0 + wn + n * 16 + (lane & 15);
        float v = acc[m][n][j] + bias[col];
        if (RELU) v = fmaxf(v, 0.f);
        C[(size_t)row * N + col] = __float2bfloat16(v);
      }
    }
  }
}

// ---------------- GEMM2 fused with final-dot, BN=256 single-pass ----------------
// One 512-thread block (8 waves, 2m x 4n of 64x64) computes the FULL 256-col
// output for a 128-row slab of one expert, so h1 is read exactly once, then
// reduces along cols against tW[dom[row]]:
//   sPart[e_global][row] = sum_col relu(h1@W2^T + b) * tW[dom[row]][col]
__global__ __launch_bounds__(512, 2) void k_gemm2_fused(
    const bf16* __restrict__ A,   // h1 chunk base: [Gc][8192][512]
    const bf16* __restrict__ Bt,  // eW2t chunk base: [Gc][256][512]
    const float* __restrict__ bias,  // eb2 chunk base: [Gc][256]
    const float* __restrict__ tW, const int* __restrict__ dom_ids,
    float* __restrict__ sPart, int e_base) {
  __shared__ __align__(16) short sA[128 * 64];   // 16 KB = 1024 16B-chunks
  __shared__ __align__(16) short sB[256 * 64];   // 32 KB = 2048 16B-chunks
  __shared__ float sTW[8][256];                  //  8 KB
  __shared__ int   sdom[128];
  __shared__ float sRed[4][128];                 //  2 KB

  const int tid = threadIdx.x;          // 0..511
  const int wave = tid >> 6, lane = tid & 63;

  const int nwg = gridDim.x * gridDim.y;
  int fid = blockIdx.x + gridDim.x * blockIdx.y;
  int nid = xcd_swizzle(fid, nwg);
  const int m0 = (nid % 64) * 128;
  const int e  = nid / 64;

  A    += (size_t)e * (8192LL * 512);
  Bt   += (size_t)e * (256LL * 512);
  bias += e * 256;

  // stage tW (full 8x256) + dom ids for this row range
  for (int i = tid; i < 8 * 256; i += 512)
    sTW[i >> 8][i & 255] = tW[i];
  if (tid < 128) sdom[tid] = dom_ids[m0 + tid];

  const int wm = (wave & 1) * 64, wn = (wave >> 1) * 64;

  f32x4 acc[4][4];
  #pragma unroll
  for (int m = 0; m < 4; ++m)
    #pragma unroll
    for (int n = 0; n < 4; ++n)
      acc[m][n] = (f32x4){0.f, 0.f, 0.f, 0.f};

  for (int kt = 0; kt < 8; ++kt) {      // K = 512, BK = 64
    const int k0 = kt << 6;
    // stage A: 128 rows x 64 cols bf16 = 1024 chunks of 16B -> 2 per thread
    #pragma unroll
    for (int c = 0; c < 2; ++c) {
      int i = c * 512 + tid;
      int r = i >> 3, col = (i & 7) * 8;
      gload_lds16(A + (size_t)(m0 + r) * 512 + k0 + col,
                  (char*)sA + (c * 512 + wave * 64) * 16);
    }
    // stage B: 256 rows x 64 cols bf16 = 2048 chunks of 16B -> 4 per thread
    #pragma unroll
    for (int c = 0; c < 4; ++c) {
      int i = c * 512 + tid;
      int r = i >> 3, col = (i & 7) * 8;
      gload_lds16(Bt + (size_t)r * 512 + k0 + col,
                  (char*)sB + (c * 512 + wave * 64) * 16);
    }
    __syncthreads();

    #pragma unroll
    for (int ks = 0; ks < 2; ++ks) {
      const int kb = ks * 32 + (lane >> 4) * 8;
      short8 af[4], bfr[4];
      #pragma unroll
      for (int m = 0; m < 4; ++m)
        af[m] = *(const short8*)&sA[(wm + m * 16 + (lane & 15)) * 64 + kb];
      #pragma unroll
      for (int n = 0; n < 4; ++n)
        bfr[n] = *(const short8*)&sB[(wn + n * 16 + (lane & 15)) * 64 + kb];
      #pragma unroll
      for (int m = 0; m < 4; ++m)
        #pragma unroll
        for (int n = 0; n < 4; ++n)
          acc[m][n] = __builtin_amdgcn_mfma_f32_16x16x32_bf16(af[m], bfr[n], acc[m][n], 0, 0, 0);
    }
    __syncthreads();
  }

  // fused epilogue: rowsum over this wave's 64 cols
  float rowsum[4][4];
  #pragma unroll
  for (int m = 0; m < 4; ++m) {
    #pragma unroll
    for (int j = 0; j < 4; ++j) {
      int rl = wm + m * 16 + (lane >> 4) * 4 + j;
      int dm = sdom[rl];
      float rs = 0.f;
      #pragma unroll
      for (int n = 0; n < 4; ++n) {
        int cl = wn + n * 16 + (lane & 15);
        float v = fmaxf(acc[m][n][j] + bias[cl], 0.f);
        rs += v * sTW[dm][cl];
      }
      rowsum[m][j] = rs;
    }
  }
  // reduce across the 16 lanes holding different cols of the same row
  #pragma unroll
  for (int m = 0; m < 4; ++m)
    #pragma unroll
    for (int j = 0; j < 4; ++j) {
      float v = rowsum[m][j];
      #pragma unroll
      for (int off = 1; off < 16; off <<= 1)
        v += __shfl_xor(v, off);
      rowsum[m][j] = v;
    }
  // each wave deposits its 64-row partial into its n-column slot
  // (the two waves of each ncol group cover disjoint row halves via wm)
  const int ncol = wave >> 1;
  if ((lane & 15) == 0) {
    #pragma unroll
    for (int m = 0; m < 4; ++m)
      #pragma unroll
      for (int j = 0; j < 4; ++j)
        sRed[ncol][wm + m * 16 + (lane >> 4) * 4 + j] = rowsum[m][j];
  }
  __syncthreads();
  if (tid < 128) {
    float v = sRed[0][tid] + sRed[1][tid] + sRed[2][tid] + sRed[3][tid];
    sPart[(size_t)(e_base + e) * 8192 + m0 + tid] = v;
  }
}

// ---------------- gating layer 2 + combine -> w[b][20] ----------------
__global__ void k_gating2(const bf16* __restrict__ gh,
                          const float* __restrict__ gW2, const float* __restrict__ gb2,
                          const float* __restrict__ lW2, const float* __restrict__ lb2,
                          float* __restrict__ wout) {
  const int b = blockIdx.x, lane = threadIdx.x;  // 64 threads
  __shared__ float sg[576];
  __shared__ float spre[56];
  __shared__ float sgate[48];
  __shared__ float slg[8];
  const bf16* row = gh + (long long)b * 640;
  for (int i = lane; i < 576; i += 64) sg[i] = __bfloat162float(row[i]);
  __syncthreads();
  if (lane < 48) {
    int d = lane / 6, o = lane % 6;
    float acc = gb2[d * 6 + o];
    const float* w = gW2 + (d * 64) * 6 + o;  // gW2[d][g][o]
    #pragma unroll 8
    for (int g = 0; g < 64; ++g) acc += sg[d * 64 + g] * w[g * 6];
    spre[lane] = acc;
  } else if (lane < 56) {
    int dd = lane - 48;
    float acc = lb2[dd];
    #pragma unroll 8
    for (int g = 0; g < 64; ++g) acc += sg[512 + g] * lW2[g * 8 + dd];
    spre[lane] = acc;
  }
  __syncthreads();
  if (lane < 8) {  // softmax over 6 domain-gate outputs
    float mx = -1e30f;
    #pragma unroll
    for (int o = 0; o < 6; ++o) mx = fmaxf(mx, spre[lane * 6 + o]);
    float s = 0.f, ev[6];
    #pragma unroll
    for (int o = 0; o < 6; ++o) { ev[o] = expf(spre[lane * 6 + o] - mx); s += ev[o]; }
    float inv = 1.f / s;
    #pragma unroll
    for (int o = 0; o < 6; ++o) sgate[lane * 6 + o] = ev[o] * inv;
  } else if (lane == 8) {  // local softmax over 8 domains
    float mx = -1e30f;
    #pragma unroll
    for (int d = 0; d < 8; ++d) mx = fmaxf(mx, spre[48 + d]);
    float s = 0.f, ev[8];
    #pragma unroll
    for (int d = 0; d < 8; ++d) { ev[d] = expf(spre[48 + d] - mx); s += ev[d]; }
    float inv = 1.f / s;
    #pragma unroll
    for (int d = 0; d < 8; ++d) slg[d] = ev[d] * inv;
  }
  __syncthreads();
  if (lane < 20) {
    float wv;
    if (lane < 4) {
      wv = 0.f;
      #pragma unroll
      for (int d = 0; d < 8; ++d) wv += slg[d] * sgate[d * 6 + lane];
    } else {
      int idx = lane - 4, d = idx >> 1, ei = idx & 1;
      wv = slg[d] * sgate[d * 6 + 4 + ei];
    }
    wout[(long long)b * 20 + lane] = wv;
  }
}

// ---------------- final: logits + sigmoid ----------------
__global__ void k_final2(const float* __restrict__ sPart, const float* __restrict__ wgt,
                         const int* __restrict__ dom_ids, const float* __restrict__ tb,
                         float* __restrict__ out) {
  int b = blockIdx.x * 256 + threadIdx.x;  // grid 32 x 256 = 8192
  int dom = dom_ids[b];
  float acc = tb[dom];
  const float* w = wgt + (size_t)b * 20;
  #pragma unroll
  for (int e = 0; e < 20; ++e)
    acc += w[e] * sPart[(size_t)e * 8192 + b];
  out[b] = 1.f / (1.f + expf(-acc));
}

// ---------------- launch ----------------

extern "C" void kernel_launch(void* const* d_in, const int* in_sizes, int n_in,
                              void* d_out, int out_size, void* d_ws, size_t ws_size,
                              hipStream_t stream) {
  const float* x   = (const float*)d_in[0];
  const int*   dom = (const int*)d_in[1];
  const float* eW1 = (const float*)d_in[2];
  const float* eb1 = (const float*)d_in[3];
  const float* eW2 = (const float*)d_in[4];
  const float* eb2 = (const float*)d_in[5];
  const float* gW1 = (const float*)d_in[6];
  const float* gb1 = (const float*)d_in[7];
  const float* gW2 = (const float*)d_in[8];
  const float* gb2 = (const float*)d_in[9];
  const float* lW1 = (const float*)d_in[10];
  const float* lb1 = (const float*)d_in[11];
  const float* lW2 = (const float*)d_in[12];
  const float* lb2 = (const float*)d_in[13];
  const float* tW  = (const float*)d_in[14];
  const float* tb  = (const float*)d_in[15];
  float* out = (float*)d_out;

  char* ws = (char*)d_ws;
  size_t off = 0;
  auto alloc = [&](size_t bytes) -> char* {
    char* p = ws + off;
    off += (bytes + 255) / 256 * 256;
    return p;
  };
  bf16*  xb    = (bf16*) alloc((size_t)8192 * 1024 * 2);        // 16.8 MB
  bf16*  eW1t  = (bf16*) alloc((size_t)20 * 512 * 1024 * 2);    // 21.0 MB [e][512][1024]
  bf16*  eW2t  = (bf16*) alloc((size_t)20 * 256 * 512 * 2);     //  5.2 MB [e][256][512]
  bf16*  Wgt   = (bf16*) alloc((size_t)640 * 1024 * 2);         //  1.3 MB [640][1024]
  float* gbias = (float*)alloc(640 * 4);
  bf16*  gh    = (bf16*) alloc((size_t)8192 * 640 * 2);         // 10.5 MB
  float* wgt   = (float*)alloc((size_t)8192 * 20 * 4);          //  0.7 MB
  float* sPart = (float*)alloc((size_t)20 * 8192 * 4);          //  0.65 MB
  // adaptive expert chunk for h1 reuse (deterministic per ws_size -> capture-safe)
  const size_t per_e = (size_t)8192 * 512 * 2;                  //  8.4 MB / expert
  int G = 20;
  {
    size_t avail = (ws_size > off) ? (ws_size - off) : 0;
    size_t g = avail / per_e;
    if (g < 1) g = 1;
    if (g > 20) g = 20;
    G = (int)g;
  }
  bf16* h1 = (bf16*)alloc(per_e * G);                           // [G][B][512]

  // prep: convert + transpose weights to [N][K] bf16
  k_convert_bf16<<<8192, 256, 0, stream>>>(x, xb, 8192 * 1024);
  k_transpose_to_bf16<<<dim3(16, 32, 20), dim3(32, 8), 0, stream>>>(
      eW1, eW1t, 1024, 512, 1024LL * 512, 512LL * 1024);
  k_transpose_to_bf16<<<dim3(8, 16, 20), dim3(32, 8), 0, stream>>>(
      eW2, eW2t, 512, 256, 512LL * 256, 256LL * 512);
  k_transpose_to_bf16<<<dim3(2, 32, 8), dim3(32, 8), 0, stream>>>(
      gW1, Wgt, 1024, 64, 1024LL * 64, 64LL * 1024);
  k_transpose_to_bf16<<<dim3(2, 32, 1), dim3(32, 8), 0, stream>>>(
      lW1, Wgt + 512 * 1024, 1024, 64, 0, 0);
  k_pack_misc<<<256, 256, 0, stream>>>(gb1, lb1, gbias, Wgt);

  // gating: gh = relu(x @ Wg^T + gbias); then layer-2 + softmax combine -> w[b][20]
  k_gemm_bt<true><<<dim3(5, 64, 1), 256, 0, stream>>>(
      xb, 0, 1024, Wgt, 0, gbias, 0, gh, 0, 640, 1024);
  k_gating2<<<8192, 64, 0, stream>>>(gh, gW2, gb2, lW2, lb2, wgt);

  // expert MLP in chunks of G experts, h1 reused per chunk
  for (int base = 0; base < 20; base += G) {
    int Gc = (20 - base < G) ? (20 - base) : G;
    k_gemm_bt<true><<<dim3(4, 64, Gc), 256, 0, stream>>>(
        xb, 0, 1024, eW1t + (size_t)base * 512 * 1024, 512LL * 1024,
        eb1 + base * 512, 512, h1, 8192LL * 512, 512, 1024);
    k_gemm2_fused<<<dim3(64, Gc), 512, 0, stream>>>(
        h1, eW2t + (size_t)base * 256 * 512,
        eb2 + base * 256, tW, dom, sPart, base);
  }

  // final: logits + sigmoid
  k_final2<<<32, 256, 0, stream>>>(sPart, wgt, dom, tb, out);
}

// Round 14
// 489.167 us; speedup vs baseline: 1.0269x; 1.0269x over previous
//
#include <hip/hip_runtime.h>
#include <hip/hip_bf16.h>

typedef __hip_bfloat16 bf16;
typedef __attribute__((ext_vector_type(8))) short short8;
typedef __attribute__((ext_vector_type(4))) float f32x4;

#define DEVINL __device__ __forceinline__

// async global->LDS, 16B per lane. LDS dest must be wave-uniform base; HW adds lane*16.
DEVINL void gload_lds16(const void* g, void* lds) {
  __builtin_amdgcn_global_load_lds(
      (const __attribute__((address_space(1))) unsigned int*)g,
      (__attribute__((address_space(3))) unsigned int*)lds,
      16, 0, 0);
}

// XCD-aware chunked swizzle (T1). fid = physical flat block id; returns logical id.
// Requires nwg % 8 == 0 for bijectivity; falls back to identity otherwise.
DEVINL int xcd_swizzle(int fid, int nwg) {
  if (nwg & 7) return fid;
  return (fid & 7) * (nwg >> 3) + (fid >> 3);
}

// ---------------- prep kernels ----------------

__global__ void k_convert_bf16(const float* __restrict__ in, bf16* __restrict__ out, int n) {
  int i = (blockIdx.x * blockDim.x + threadIdx.x) * 4;
  if (i + 3 < n) {
    float4 v = *(const float4*)(in + i);
    out[i + 0] = __float2bfloat16(v.x);
    out[i + 1] = __float2bfloat16(v.y);
    out[i + 2] = __float2bfloat16(v.z);
    out[i + 3] = __float2bfloat16(v.w);
  }
}

// out[b][c][r] = in[b][r][c], f32 -> bf16. R,C multiples of 32.
__global__ void k_transpose_to_bf16(const float* __restrict__ in, bf16* __restrict__ out,
                                    int R, int C, long long in_bstride, long long out_bstride) {
  __shared__ float tile[32][33];
  in  += (long long)blockIdx.z * in_bstride;
  out += (long long)blockIdx.z * out_bstride;
  int c0 = blockIdx.x * 32, r0 = blockIdx.y * 32;
  int tx = threadIdx.x, ty = threadIdx.y;  // 32x8
  #pragma unroll
  for (int i = ty; i < 32; i += 8)
    tile[i][tx] = in[(long long)(r0 + i) * C + c0 + tx];
  __syncthreads();
  #pragma unroll
  for (int i = ty; i < 32; i += 8)
    out[(long long)(c0 + i) * R + r0 + tx] = __float2bfloat16(tile[tx][i]);
}

// build gating bias vector (640) and zero pad rows 576..639 of Wgt
__global__ void k_pack_misc(const float* __restrict__ gb1, const float* __restrict__ lb1,
                            float* __restrict__ gbias, bf16* __restrict__ Wgt) {
  int i = blockIdx.x * blockDim.x + threadIdx.x;
  if (i < 640) {
    float v;
    if (i < 512) v = gb1[i];            // (D,G) flat: d*64+g
    else if (i < 576) v = lb1[i - 512]; // lb1[g]
    else v = 0.f;
    gbias[i] = v;
  }
  if (i < 64 * 1024) Wgt[576 * 1024 + i] = __float2bfloat16(0.f);
}

// ---------------- main GEMM: C = act(A @ Bt^T + bias) ----------------
// 128x128 tile, BK=64, 256 threads (4 waves, each 64x64 out). XCD-swizzled.
template <bool RELU>
__global__ __launch_bounds__(256, 2) void k_gemm_bt(
    const bf16* __restrict__ A, long long a_bstride, int lda,
    const bf16* __restrict__ Bt, long long b_bstride,
    const float* __restrict__ bias, long long bias_bstride,
    bf16* __restrict__ C, long long c_bstride,
    int N, int K) {
  __shared__ __align__(16) short sA[128 * 64];
  __shared__ __align__(16) short sB[128 * 64];

  const int tid = threadIdx.x;
  const int wave = tid >> 6, lane = tid & 63;

  // XCD-aware block remap (keeps n fastest so A-sharing blocks stay on one XCD)
  const int nwg = gridDim.x * gridDim.y * gridDim.z;
  int fid = blockIdx.x + gridDim.x * (blockIdx.y + gridDim.y * blockIdx.z);
  int nid = xcd_swizzle(fid, nwg);
  const int bx = nid % gridDim.x;  nid /= gridDim.x;
  const int by = nid % gridDim.y;
  const int e  = nid / gridDim.y;
  const int m0 = by * 128, n0 = bx * 128;

  A    += (long long)e * a_bstride;
  Bt   += (long long)e * b_bstride;
  bias += (long long)e * bias_bstride;
  C    += (long long)e * c_bstride;

  const int wm = (wave >> 1) * 64, wn = (wave & 1) * 64;

  f32x4 acc[4][4];
  #pragma unroll
  for (int m = 0; m < 4; ++m)
    #pragma unroll
    for (int n = 0; n < 4; ++n)
      acc[m][n] = (f32x4){0.f, 0.f, 0.f, 0.f};

  const int KT = K >> 6;
  for (int kt = 0; kt < KT; ++kt) {
    const int k0 = kt << 6;
    #pragma unroll
    for (int c = 0; c < 4; ++c) {
      int i = c * 256 + tid;
      int r = i >> 3, col = (i & 7) * 8;
      gload_lds16(A + (size_t)(m0 + r) * lda + k0 + col,
                  (char*)sA + (c * 256 + wave * 64) * 16);
    }
    #pragma unroll
    for (int c = 0; c < 4; ++c) {
      int i = c * 256 + tid;
      int r = i >> 3, col = (i & 7) * 8;
      gload_lds16(Bt + (size_t)(n0 + r) * K + k0 + col,
                  (char*)sB + (c * 256 + wave * 64) * 16);
    }
    __syncthreads();

    #pragma unroll
    for (int ks = 0; ks < 2; ++ks) {
      const int kb = ks * 32 + (lane >> 4) * 8;
      short8 af[4], bfr[4];
      #pragma unroll
      for (int m = 0; m < 4; ++m)
        af[m] = *(const short8*)&sA[(wm + m * 16 + (lane & 15)) * 64 + kb];
      #pragma unroll
      for (int n = 0; n < 4; ++n)
        bfr[n] = *(const short8*)&sB[(wn + n * 16 + (lane & 15)) * 64 + kb];
      #pragma unroll
      for (int m = 0; m < 4; ++m)
        #pragma unroll
        for (int n = 0; n < 4; ++n)
          acc[m][n] = __builtin_amdgcn_mfma_f32_16x16x32_bf16(af[m], bfr[n], acc[m][n], 0, 0, 0);
    }
    __syncthreads();
  }

  // epilogue: C/D layout col=lane&15, row=(lane>>4)*4+j
  #pragma unroll
  for (int m = 0; m < 4; ++m) {
    #pragma unroll
    for (int n = 0; n < 4; ++n) {
      #pragma unroll
      for (int j = 0; j < 4; ++j) {
        int row = m0 + wm + m * 16 + (lane >> 4) * 4 + j;
        int col = n0 + wn + n * 16 + (lane & 15);
        float v = acc[m][n][j] + bias[col];
        if (RELU) v = fmaxf(v, 0.f);
        C[(size_t)row * N + col] = __float2bfloat16(v);
      }
    }
  }
}

// ---------------- GEMM2 fused with final-dot, 64-row slab x 256 cols ----------------
// 256 threads (4 waves). Each wave owns one 64x64 n-quadrant of the SAME 64 rows,
// so the block computes relu(h1[64rows] @ W2^T + b) for the full 256 cols in one
// pass (h1 read once) and reduces along cols against tW[dom[row]]:
//   sPart[e_global][row] = sum_col relu(...) * tW[dom[row]][col]
// LDS ~49 KB -> 3 blocks/CU; grid 128*Gc blocks -> good cross-block overlap.
__global__ __launch_bounds__(256, 2) void k_gemm2_fused(
    const bf16* __restrict__ A,   // h1 chunk base: [Gc][8192][512]
    const bf16* __restrict__ Bt,  // eW2t chunk base: [Gc][256][512]
    const float* __restrict__ bias,  // eb2 chunk base: [Gc][256]
    const float* __restrict__ tW, const int* __restrict__ dom_ids,
    float* __restrict__ sPart, int e_base) {
  __shared__ __align__(16) short sA[64 * 64];    //  8 KB =  512 16B-chunks
  __shared__ __align__(16) short sB[256 * 64];   // 32 KB = 2048 16B-chunks
  __shared__ float sTW[8][256];                  //  8 KB
  __shared__ int   sdom[64];
  __shared__ float sRed[4][64];                  //  1 KB

  const int tid = threadIdx.x;          // 0..255
  const int wave = tid >> 6, lane = tid & 63;

  const int nwg = gridDim.x * gridDim.y;   // 128*Gc, always % 8 == 0
  int fid = blockIdx.x + gridDim.x * blockIdx.y;
  int nid = xcd_swizzle(fid, nwg);
  const int m0 = (nid % 128) * 64;
  const int e  = nid / 128;

  A    += (size_t)e * (8192LL * 512);
  Bt   += (size_t)e * (256LL * 512);
  bias += e * 256;

  // stage tW (full 8x256) + dom ids for this row range
  for (int i = tid; i < 8 * 256; i += 256)
    sTW[i >> 8][i & 255] = tW[i];
  if (tid < 64) sdom[tid] = dom_ids[m0 + tid];

  const int wn = wave * 64;   // wave's n-quadrant; all waves share rows 0..63

  f32x4 acc[4][4];
  #pragma unroll
  for (int m = 0; m < 4; ++m)
    #pragma unroll
    for (int n = 0; n < 4; ++n)
      acc[m][n] = (f32x4){0.f, 0.f, 0.f, 0.f};

  for (int kt = 0; kt < 8; ++kt) {      // K = 512, BK = 64
    const int k0 = kt << 6;
    // stage A: 64 rows x 64 cols bf16 = 512 chunks of 16B -> 2 per thread
    #pragma unroll
    for (int c = 0; c < 2; ++c) {
      int i = c * 256 + tid;
      int r = i >> 3, col = (i & 7) * 8;
      gload_lds16(A + (size_t)(m0 + r) * 512 + k0 + col,
                  (char*)sA + (c * 256 + wave * 64) * 16);
    }
    // stage B: 256 rows x 64 cols bf16 = 2048 chunks of 16B -> 8 per thread
    #pragma unroll
    for (int c = 0; c < 8; ++c) {
      int i = c * 256 + tid;
      int r = i >> 3, col = (i & 7) * 8;
      gload_lds16(Bt + (size_t)r * 512 + k0 + col,
                  (char*)sB + (c * 256 + wave * 64) * 16);
    }
    __syncthreads();

    #pragma unroll
    for (int ks = 0; ks < 2; ++ks) {
      const int kb = ks * 32 + (lane >> 4) * 8;
      short8 af[4], bfr[4];
      #pragma unroll
      for (int m = 0; m < 4; ++m)
        af[m] = *(const short8*)&sA[(m * 16 + (lane & 15)) * 64 + kb];
      #pragma unroll
      for (int n = 0; n < 4; ++n)
        bfr[n] = *(const short8*)&sB[(wn + n * 16 + (lane & 15)) * 64 + kb];
      #pragma unroll
      for (int m = 0; m < 4; ++m)
        #pragma unroll
        for (int n = 0; n < 4; ++n)
          acc[m][n] = __builtin_amdgcn_mfma_f32_16x16x32_bf16(af[m], bfr[n], acc[m][n], 0, 0, 0);
    }
    __syncthreads();
  }

  // fused epilogue: rowsum over this wave's 64 cols
  float rowsum[4][4];
  #pragma unroll
  for (int m = 0; m < 4; ++m) {
    #pragma unroll
    for (int j = 0; j < 4; ++j) {
      int rl = m * 16 + (lane >> 4) * 4 + j;
      int dm = sdom[rl];
      float rs = 0.f;
      #pragma unroll
      for (int n = 0; n < 4; ++n) {
        int cl = wn + n * 16 + (lane & 15);
        float v = fmaxf(acc[m][n][j] + bias[cl], 0.f);
        rs += v * sTW[dm][cl];
      }
      rowsum[m][j] = rs;
    }
  }
  // reduce across the 16 lanes holding different cols of the same row
  #pragma unroll
  for (int m = 0; m < 4; ++m)
    #pragma unroll
    for (int j = 0; j < 4; ++j) {
      float v = rowsum[m][j];
      #pragma unroll
      for (int off = 1; off < 16; off <<= 1)
        v += __shfl_xor(v, off);
      rowsum[m][j] = v;
    }
  // each wave deposits its 64-row partial into its n-quadrant slot
  if ((lane & 15) == 0) {
    #pragma unroll
    for (int m = 0; m < 4; ++m)
      #pragma unroll
      for (int j = 0; j < 4; ++j)
        sRed[wave][m * 16 + (lane >> 4) * 4 + j] = rowsum[m][j];
  }
  __syncthreads();
  if (tid < 64) {
    float v = sRed[0][tid] + sRed[1][tid] + sRed[2][tid] + sRed[3][tid];
    sPart[(size_t)(e_base + e) * 8192 + m0 + tid] = v;
  }
}

// ---------------- gating layer 2 + combine -> w[b][20] ----------------
__global__ void k_gating2(const bf16* __restrict__ gh,
                          const float* __restrict__ gW2, const float* __restrict__ gb2,
                          const float* __restrict__ lW2, const float* __restrict__ lb2,
                          float* __restrict__ wout) {
  const int b = blockIdx.x, lane = threadIdx.x;  // 64 threads
  __shared__ float sg[576];
  __shared__ float spre[56];
  __shared__ float sgate[48];
  __shared__ float slg[8];
  const bf16* row = gh + (long long)b * 640;
  for (int i = lane; i < 576; i += 64) sg[i] = __bfloat162float(row[i]);
  __syncthreads();
  if (lane < 48) {
    int d = lane / 6, o = lane % 6;
    float acc = gb2[d * 6 + o];
    const float* w = gW2 + (d * 64) * 6 + o;  // gW2[d][g][o]
    #pragma unroll 8
    for (int g = 0; g < 64; ++g) acc += sg[d * 64 + g] * w[g * 6];
    spre[lane] = acc;
  } else if (lane < 56) {
    int dd = lane - 48;
    float acc = lb2[dd];
    #pragma unroll 8
    for (int g = 0; g < 64; ++g) acc += sg[512 + g] * lW2[g * 8 + dd];
    spre[lane] = acc;
  }
  __syncthreads();
  if (lane < 8) {  // softmax over 6 domain-gate outputs
    float mx = -1e30f;
    #pragma unroll
    for (int o = 0; o < 6; ++o) mx = fmaxf(mx, spre[lane * 6 + o]);
    float s = 0.f, ev[6];
    #pragma unroll
    for (int o = 0; o < 6; ++o) { ev[o] = expf(spre[lane * 6 + o] - mx); s += ev[o]; }
    float inv = 1.f / s;
    #pragma unroll
    for (int o = 0; o < 6; ++o) sgate[lane * 6 + o] = ev[o] * inv;
  } else if (lane == 8) {  // local softmax over 8 domains
    float mx = -1e30f;
    #pragma unroll
    for (int d = 0; d < 8; ++d) mx = fmaxf(mx, spre[48 + d]);
    float s = 0.f, ev[8];
    #pragma unroll
    for (int d = 0; d < 8; ++d) { ev[d] = expf(spre[48 + d] - mx); s += ev[d]; }
    float inv = 1.f / s;
    #pragma unroll
    for (int d = 0; d < 8; ++d) slg[d] = ev[d] * inv;
  }
  __syncthreads();
  if (lane < 20) {
    float wv;
    if (lane < 4) {
      wv = 0.f;
      #pragma unroll
      for (int d = 0; d < 8; ++d) wv += slg[d] * sgate[d * 6 + lane];
    } else {
      int idx = lane - 4, d = idx >> 1, ei = idx & 1;
      wv = slg[d] * sgate[d * 6 + 4 + ei];
    }
    wout[(long long)b * 20 + lane] = wv;
  }
}

// ---------------- final: logits + sigmoid ----------------
__global__ void k_final2(const float* __restrict__ sPart, const float* __restrict__ wgt,
                         const int* __restrict__ dom_ids, const float* __restrict__ tb,
                         float* __restrict__ out) {
  int b = blockIdx.x * 256 + threadIdx.x;  // grid 32 x 256 = 8192
  int dom = dom_ids[b];
  float acc = tb[dom];
  const float* w = wgt + (size_t)b * 20;
  #pragma unroll
  for (int e = 0; e < 20; ++e)
    acc += w[e] * sPart[(size_t)e * 8192 + b];
  out[b] = 1.f / (1.f + expf(-acc));
}

// ---------------- launch ----------------

extern "C" void kernel_launch(void* const* d_in, const int* in_sizes, int n_in,
                              void* d_out, int out_size, void* d_ws, size_t ws_size,
                              hipStream_t stream) {
  const float* x   = (const float*)d_in[0];
  const int*   dom = (const int*)d_in[1];
  const float* eW1 = (const float*)d_in[2];
  const float* eb1 = (const float*)d_in[3];
  const float* eW2 = (const float*)d_in[4];
  const float* eb2 = (const float*)d_in[5];
  const float* gW1 = (const float*)d_in[6];
  const float* gb1 = (const float*)d_in[7];
  const float* gW2 = (const float*)d_in[8];
  const float* gb2 = (const float*)d_in[9];
  const float* lW1 = (const float*)d_in[10];
  const float* lb1 = (const float*)d_in[11];
  const float* lW2 = (const float*)d_in[12];
  const float* lb2 = (const float*)d_in[13];
  const float* tW  = (const float*)d_in[14];
  const float* tb  = (const float*)d_in[15];
  float* out = (float*)d_out;

  char* ws = (char*)d_ws;
  size_t off = 0;
  auto alloc = [&](size_t bytes) -> char* {
    char* p = ws + off;
    off += (bytes + 255) / 256 * 256;
    return p;
  };
  bf16*  xb    = (bf16*) alloc((size_t)8192 * 1024 * 2);        // 16.8 MB
  bf16*  eW1t  = (bf16*) alloc((size_t)20 * 512 * 1024 * 2);    // 21.0 MB [e][512][1024]
  bf16*  eW2t  = (bf16*) alloc((size_t)20 * 256 * 512 * 2);     //  5.2 MB [e][256][512]
  bf16*  Wgt   = (bf16*) alloc((size_t)640 * 1024 * 2);         //  1.3 MB [640][1024]
  float* gbias = (float*)alloc(640 * 4);
  bf16*  gh    = (bf16*) alloc((size_t)8192 * 640 * 2);         // 10.5 MB
  float* wgt   = (float*)alloc((size_t)8192 * 20 * 4);          //  0.7 MB
  float* sPart = (float*)alloc((size_t)20 * 8192 * 4);          //  0.65 MB
  // adaptive expert chunk for h1 reuse (deterministic per ws_size -> capture-safe)
  const size_t per_e = (size_t)8192 * 512 * 2;                  //  8.4 MB / expert
  int G = 20;
  {
    size_t avail = (ws_size > off) ? (ws_size - off) : 0;
    size_t g = avail / per_e;
    if (g < 1) g = 1;
    if (g > 20) g = 20;
    G = (int)g;
  }
  bf16* h1 = (bf16*)alloc(per_e * G);                           // [G][B][512]

  // prep: convert + transpose weights to [N][K] bf16
  k_convert_bf16<<<8192, 256, 0, stream>>>(x, xb, 8192 * 1024);
  k_transpose_to_bf16<<<dim3(16, 32, 20), dim3(32, 8), 0, stream>>>(
      eW1, eW1t, 1024, 512, 1024LL * 512, 512LL * 1024);
  k_transpose_to_bf16<<<dim3(8, 16, 20), dim3(32, 8), 0, stream>>>(
      eW2, eW2t, 512, 256, 512LL * 256, 256LL * 512);
  k_transpose_to_bf16<<<dim3(2, 32, 8), dim3(32, 8), 0, stream>>>(
      gW1, Wgt, 1024, 64, 1024LL * 64, 64LL * 1024);
  k_transpose_to_bf16<<<dim3(2, 32, 1), dim3(32, 8), 0, stream>>>(
      lW1, Wgt + 512 * 1024, 1024, 64, 0, 0);
  k_pack_misc<<<256, 256, 0, stream>>>(gb1, lb1, gbias, Wgt);

  // gating: gh = relu(x @ Wg^T + gbias); then layer-2 + softmax combine -> w[b][20]
  k_gemm_bt<true><<<dim3(5, 64, 1), 256, 0, stream>>>(
      xb, 0, 1024, Wgt, 0, gbias, 0, gh, 0, 640, 1024);
  k_gating2<<<8192, 64, 0, stream>>>(gh, gW2, gb2, lW2, lb2, wgt);

  // expert MLP in chunks of G experts, h1 reused per chunk
  for (int base = 0; base < 20; base += G) {
    int Gc = (20 - base < G) ? (20 - base) : G;
    k_gemm_bt<true><<<dim3(4, 64, Gc), 256, 0, stream>>>(
        xb, 0, 1024, eW1t + (size_t)base * 512 * 1024, 512LL * 1024,
        eb1 + base * 512, 512, h1, 8192LL * 512, 512, 1024);
    k_gemm2_fused<<<dim3(128, Gc), 256, 0, stream>>>(
        h1, eW2t + (size_t)base * 256 * 512,
        eb2 + base * 256, tW, dom, sPart, base);
  }

  // final: logits + sigmoid
  k_final2<<<32, 256, 0, stream>>>(sPart, wgt, dom, tb, out);
}

// Round 18
// 473.133 us; speedup vs baseline: 1.0617x; 1.0339x over previous
//
#include <hip/hip_runtime.h>
#include <hip/hip_bf16.h>

typedef __hip_bfloat16 bf16;
typedef __attribute__((ext_vector_type(8))) short short8;
typedef __attribute__((ext_vector_type(4))) float f32x4;

#define DEVINL __device__ __forceinline__

// async global->LDS, 16B per lane. LDS dest must be wave-uniform base; HW adds lane*16.
DEVINL void gload_lds16(const void* g, void* lds) {
  __builtin_amdgcn_global_load_lds(
      (const __attribute__((address_space(1))) unsigned int*)g,
      (__attribute__((address_space(3))) unsigned int*)lds,
      16, 0, 0);
}

// XCD-aware chunked swizzle (T1). fid = physical flat block id; returns logical id.
// Requires nwg % 8 == 0 for bijectivity; falls back to identity otherwise.
DEVINL int xcd_swizzle(int fid, int nwg) {
  if (nwg & 7) return fid;
  return (fid & 7) * (nwg >> 3) + (fid >> 3);
}

// ---------------- prep kernels ----------------

__global__ void k_convert_bf16(const float* __restrict__ in, bf16* __restrict__ out, int n) {
  int i = (blockIdx.x * blockDim.x + threadIdx.x) * 4;
  if (i + 3 < n) {
    float4 v = *(const float4*)(in + i);
    out[i + 0] = __float2bfloat16(v.x);
    out[i + 1] = __float2bfloat16(v.y);
    out[i + 2] = __float2bfloat16(v.z);
    out[i + 3] = __float2bfloat16(v.w);
  }
}

// out[b][c][r] = in[b][r][c], f32 -> bf16. R,C multiples of 32.
__global__ void k_transpose_to_bf16(const float* __restrict__ in, bf16* __restrict__ out,
                                    int R, int C, long long in_bstride, long long out_bstride) {
  __shared__ float tile[32][33];
  in  += (long long)blockIdx.z * in_bstride;
  out += (long long)blockIdx.z * out_bstride;
  int c0 = blockIdx.x * 32, r0 = blockIdx.y * 32;
  int tx = threadIdx.x, ty = threadIdx.y;  // 32x8
  #pragma unroll
  for (int i = ty; i < 32; i += 8)
    tile[i][tx] = in[(long long)(r0 + i) * C + c0 + tx];
  __syncthreads();
  #pragma unroll
  for (int i = ty; i < 32; i += 8)
    out[(long long)(c0 + i) * R + r0 + tx] = __float2bfloat16(tile[tx][i]);
}

// build gating bias vector (640) and zero pad rows 576..639 of Wgt
__global__ void k_pack_misc(const float* __restrict__ gb1, const float* __restrict__ lb1,
                            float* __restrict__ gbias, bf16* __restrict__ Wgt) {
  int i = blockIdx.x * blockDim.x + threadIdx.x;
  if (i < 640) {
    float v;
    if (i < 512) v = gb1[i];            // (D,G) flat: d*64+g
    else if (i < 576) v = lb1[i - 512]; // lb1[g]
    else v = 0.f;
    gbias[i] = v;
  }
  if (i < 64 * 1024) Wgt[576 * 1024 + i] = __float2bfloat16(0.f);
}

// ---------------- main GEMM: C = act(A @ Bt^T + bias) ----------------
// 128x128 tile, BK=64, 256 threads (4 waves, each 64x64 out). XCD-swizzled.
template <bool RELU>
__global__ __launch_bounds__(256, 2) void k_gemm_bt(
    const bf16* __restrict__ A, long long a_bstride, int lda,
    const bf16* __restrict__ Bt, long long b_bstride,
    const float* __restrict__ bias, long long bias_bstride,
    bf16* __restrict__ C, long long c_bstride,
    int N, int K) {
  __shared__ __align__(16) short sA[128 * 64];
  __shared__ __align__(16) short sB[128 * 64];

  const int tid = threadIdx.x;
  const int wave = tid >> 6, lane = tid & 63;

  // XCD-aware block remap (keeps n fastest so A-sharing blocks stay on one XCD)
  const int nwg = gridDim.x * gridDim.y * gridDim.z;
  int fid = blockIdx.x + gridDim.x * (blockIdx.y + gridDim.y * blockIdx.z);
  int nid = xcd_swizzle(fid, nwg);
  const int bx = nid % gridDim.x;  nid /= gridDim.x;
  const int by = nid % gridDim.y;
  const int e  = nid / gridDim.y;
  const int m0 = by * 128, n0 = bx * 128;

  A    += (long long)e * a_bstride;
  Bt   += (long long)e * b_bstride;
  bias += (long long)e * bias_bstride;
  C    += (long long)e * c_bstride;

  const int wm = (wave >> 1) * 64, wn = (wave & 1) * 64;

  f32x4 acc[4][4];
  #pragma unroll
  for (int m = 0; m < 4; ++m)
    #pragma unroll
    for (int n = 0; n < 4; ++n)
      acc[m][n] = (f32x4){0.f, 0.f, 0.f, 0.f};

  const int KT = K >> 6;
  for (int kt = 0; kt < KT; ++kt) {
    const int k0 = kt << 6;
    #pragma unroll
    for (int c = 0; c < 4; ++c) {
      int i = c * 256 + tid;
      int r = i >> 3, col = (i & 7) * 8;
      gload_lds16(A + (size_t)(m0 + r) * lda + k0 + col,
                  (char*)sA + (c * 256 + wave * 64) * 16);
    }
    #pragma unroll
    for (int c = 0; c < 4; ++c) {
      int i = c * 256 + tid;
      int r = i >> 3, col = (i & 7) * 8;
      gload_lds16(Bt + (size_t)(n0 + r) * K + k0 + col,
                  (char*)sB + (c * 256 + wave * 64) * 16);
    }
    __syncthreads();

    #pragma unroll
    for (int ks = 0; ks < 2; ++ks) {
      const int kb = ks * 32 + (lane >> 4) * 8;
      short8 af[4], bfr[4];
      #pragma unroll
      for (int m = 0; m < 4; ++m)
        af[m] = *(const short8*)&sA[(wm + m * 16 + (lane & 15)) * 64 + kb];
      #pragma unroll
      for (int n = 0; n < 4; ++n)
        bfr[n] = *(const short8*)&sB[(wn + n * 16 + (lane & 15)) * 64 + kb];
      #pragma unroll
      for (int m = 0; m < 4; ++m)
        #pragma unroll
        for (int n = 0; n < 4; ++n)
          acc[m][n] = __builtin_amdgcn_mfma_f32_16x16x32_bf16(af[m], bfr[n], acc[m][n], 0, 0, 0);
    }
    __syncthreads();
  }

  // epilogue: C/D layout col=lane&15, row=(lane>>4)*4+j
  #pragma unroll
  for (int m = 0; m < 4; ++m) {
    #pragma unroll
    for (int n = 0; n < 4; ++n) {
      #pragma unroll
      for (int j = 0; j < 4; ++j) {
        int row = m0 + wm + m * 16 + (lane >> 4) * 4 + j;
        int col = n0 + wn + n * 16 + (lane & 15);
        float v = acc[m][n][j] + bias[col];
        if (RELU) v = fmaxf(v, 0.f);
        C[(size_t)row * N + col] = __float2bfloat16(v);
      }
    }
  }
}

// ---------------- GEMM2 fused with final-dot, 128-row slab x 256 cols ----------------
// 256 threads (4 waves). Each wave owns one 64-col n-quadrant of the SAME 128 rows
// (acc[8][4] per wave): A-tile staged once serves 8 m-fragments -> high MFMA:load
// ratio. Block computes relu(h1[128rows] @ W2^T + b) for all 256 cols in one pass
// (h1 read once) and reduces along cols against tW[dom[row]]:
//   sPart[e_global][row] = sum_col relu(...) * tW[dom[row]][col]
// LDS ~58.5 KB -> 2 blocks/CU; grid 64*Gc blocks.
__global__ __launch_bounds__(256, 2) void k_gemm2_fused(
    const bf16* __restrict__ A,   // h1 chunk base: [Gc][8192][512]
    const bf16* __restrict__ Bt,  // eW2t chunk base: [Gc][256][512]
    const float* __restrict__ bias,  // eb2 chunk base: [Gc][256]
    const float* __restrict__ tW, const int* __restrict__ dom_ids,
    float* __restrict__ sPart, int e_base) {
  __shared__ __align__(16) short sA[128 * 64];   // 16 KB = 1024 16B-chunks
  __shared__ __align__(16) short sB[256 * 64];   // 32 KB = 2048 16B-chunks
  __shared__ float sTW[8][256];                  //  8 KB
  __shared__ int   sdom[128];
  __shared__ float sRed[4][128];                 //  2 KB

  const int tid = threadIdx.x;          // 0..255
  const int wave = tid >> 6, lane = tid & 63;

  const int nwg = gridDim.x * gridDim.y;   // 64*Gc, always % 8 == 0
  int fid = blockIdx.x + gridDim.x * blockIdx.y;
  int nid = xcd_swizzle(fid, nwg);
  const int m0 = (nid % 64) * 128;
  const int e  = nid / 64;

  A    += (size_t)e * (8192LL * 512);
  Bt   += (size_t)e * (256LL * 512);
  bias += e * 256;

  // stage tW (full 8x256) + dom ids for this row range
  for (int i = tid; i < 8 * 256; i += 256)
    sTW[i >> 8][i & 255] = tW[i];
  if (tid < 128) sdom[tid] = dom_ids[m0 + tid];

  const int wn = wave * 64;   // wave's n-quadrant; all waves share rows 0..127

  f32x4 acc[8][4];
  #pragma unroll
  for (int m = 0; m < 8; ++m)
    #pragma unroll
    for (int n = 0; n < 4; ++n)
      acc[m][n] = (f32x4){0.f, 0.f, 0.f, 0.f};

  for (int kt = 0; kt < 8; ++kt) {      // K = 512, BK = 64
    const int k0 = kt << 6;
    // stage A: 128 rows x 64 cols bf16 = 1024 chunks of 16B -> 4 per thread
    #pragma unroll
    for (int c = 0; c < 4; ++c) {
      int i = c * 256 + tid;
      int r = i >> 3, col = (i & 7) * 8;
      gload_lds16(A + (size_t)(m0 + r) * 512 + k0 + col,
                  (char*)sA + (c * 256 + wave * 64) * 16);
    }
    // stage B: 256 rows x 64 cols bf16 = 2048 chunks of 16B -> 8 per thread
    #pragma unroll
    for (int c = 0; c < 8; ++c) {
      int i = c * 256 + tid;
      int r = i >> 3, col = (i & 7) * 8;
      gload_lds16(Bt + (size_t)r * 512 + k0 + col,
                  (char*)sB + (c * 256 + wave * 64) * 16);
    }
    __syncthreads();

    #pragma unroll
    for (int ks = 0; ks < 2; ++ks) {
      const int kb = ks * 32 + (lane >> 4) * 8;
      short8 af[8], bfr[4];
      #pragma unroll
      for (int m = 0; m < 8; ++m)
        af[m] = *(const short8*)&sA[(m * 16 + (lane & 15)) * 64 + kb];
      #pragma unroll
      for (int n = 0; n < 4; ++n)
        bfr[n] = *(const short8*)&sB[(wn + n * 16 + (lane & 15)) * 64 + kb];
      #pragma unroll
      for (int m = 0; m < 8; ++m)
        #pragma unroll
        for (int n = 0; n < 4; ++n)
          acc[m][n] = __builtin_amdgcn_mfma_f32_16x16x32_bf16(af[m], bfr[n], acc[m][n], 0, 0, 0);
    }
    __syncthreads();
  }

  // fused epilogue: rowsum over this wave's 64 cols
  float rowsum[8][4];
  #pragma unroll
  for (int m = 0; m < 8; ++m) {
    #pragma unroll
    for (int j = 0; j < 4; ++j) {
      int rl = m * 16 + (lane >> 4) * 4 + j;
      int dm = sdom[rl];
      float rs = 0.f;
      #pragma unroll
      for (int n = 0; n < 4; ++n) {
        int cl = wn + n * 16 + (lane & 15);
        float v = fmaxf(acc[m][n][j] + bias[cl], 0.f);
        rs += v * sTW[dm][cl];
      }
      rowsum[m][j] = rs;
    }
  }
  // reduce across the 16 lanes holding different cols of the same row
  #pragma unroll
  for (int m = 0; m < 8; ++m)
    #pragma unroll
    for (int j = 0; j < 4; ++j) {
      float v = rowsum[m][j];
      #pragma unroll
      for (int off = 1; off < 16; off <<= 1)
        v += __shfl_xor(v, off);
      rowsum[m][j] = v;
    }
  // each wave deposits its 128-row partial into its n-quadrant slot
  if ((lane & 15) == 0) {
    #pragma unroll
    for (int m = 0; m < 8; ++m)
      #pragma unroll
      for (int j = 0; j < 4; ++j)
        sRed[wave][m * 16 + (lane >> 4) * 4 + j] = rowsum[m][j];
  }
  __syncthreads();
  if (tid < 128) {
    float v = sRed[0][tid] + sRed[1][tid] + sRed[2][tid] + sRed[3][tid];
    sPart[(size_t)(e_base + e) * 8192 + m0 + tid] = v;
  }
}

// ---------------- gating layer 2 + combine -> w[b][20] ----------------
__global__ void k_gating2(const bf16* __restrict__ gh,
                          const float* __restrict__ gW2, const float* __restrict__ gb2,
                          const float* __restrict__ lW2, const float* __restrict__ lb2,
                          float* __restrict__ wout) {
  const int b = blockIdx.x, lane = threadIdx.x;  // 64 threads
  __shared__ float sg[576];
  __shared__ float spre[56];
  __shared__ float sgate[48];
  __shared__ float slg[8];
  const bf16* row = gh + (long long)b * 640;
  for (int i = lane; i < 576; i += 64) sg[i] = __bfloat162float(row[i]);
  __syncthreads();
  if (lane < 48) {
    int d = lane / 6, o = lane % 6;
    float acc = gb2[d * 6 + o];
    const float* w = gW2 + (d * 64) * 6 + o;  // gW2[d][g][o]
    #pragma unroll 8
    for (int g = 0; g < 64; ++g) acc += sg[d * 64 + g] * w[g * 6];
    spre[lane] = acc;
  } else if (lane < 56) {
    int dd = lane - 48;
    float acc = lb2[dd];
    #pragma unroll 8
    for (int g = 0; g < 64; ++g) acc += sg[512 + g] * lW2[g * 8 + dd];
    spre[lane] = acc;
  }
  __syncthreads();
  if (lane < 8) {  // softmax over 6 domain-gate outputs
    float mx = -1e30f;
    #pragma unroll
    for (int o = 0; o < 6; ++o) mx = fmaxf(mx, spre[lane * 6 + o]);
    float s = 0.f, ev[6];
    #pragma unroll
    for (int o = 0; o < 6; ++o) { ev[o] = expf(spre[lane * 6 + o] - mx); s += ev[o]; }
    float inv = 1.f / s;
    #pragma unroll
    for (int o = 0; o < 6; ++o) sgate[lane * 6 + o] = ev[o] * inv;
  } else if (lane == 8) {  // local softmax over 8 domains
    float mx = -1e30f;
    #pragma unroll
    for (int d = 0; d < 8; ++d) mx = fmaxf(mx, spre[48 + d]);
    float s = 0.f, ev[8];
    #pragma unroll
    for (int d = 0; d < 8; ++d) { ev[d] = expf(spre[48 + d] - mx); s += ev[d]; }
    float inv = 1.f / s;
    #pragma unroll
    for (int d = 0; d < 8; ++d) slg[d] = ev[d] * inv;
  }
  __syncthreads();
  if (lane < 20) {
    float wv;
    if (lane < 4) {
      wv = 0.f;
      #pragma unroll
      for (int d = 0; d < 8; ++d) wv += slg[d] * sgate[d * 6 + lane];
    } else {
      int idx = lane - 4, d = idx >> 1, ei = idx & 1;
      wv = slg[d] * sgate[d * 6 + 4 + ei];
    }
    wout[(long long)b * 20 + lane] = wv;
  }
}

// ---------------- final: logits + sigmoid ----------------
__global__ void k_final2(const float* __restrict__ sPart, const float* __restrict__ wgt,
                         const int* __restrict__ dom_ids, const float* __restrict__ tb,
                         float* __restrict__ out) {
  int b = blockIdx.x * 256 + threadIdx.x;  // grid 32 x 256 = 8192
  int dom = dom_ids[b];
  float acc = tb[dom];
  const float* w = wgt + (size_t)b * 20;
  #pragma unroll
  for (int e = 0; e < 20; ++e)
    acc += w[e] * sPart[(size_t)e * 8192 + b];
  out[b] = 1.f / (1.f + expf(-acc));
}

// ---------------- launch ----------------

extern "C" void kernel_launch(void* const* d_in, const int* in_sizes, int n_in,
                              void* d_out, int out_size, void* d_ws, size_t ws_size,
                              hipStream_t stream) {
  const float* x   = (const float*)d_in[0];
  const int*   dom = (const int*)d_in[1];
  const float* eW1 = (const float*)d_in[2];
  const float* eb1 = (const float*)d_in[3];
  const float* eW2 = (const float*)d_in[4];
  const float* eb2 = (const float*)d_in[5];
  const float* gW1 = (const float*)d_in[6];
  const float* gb1 = (const float*)d_in[7];
  const float* gW2 = (const float*)d_in[8];
  const float* gb2 = (const float*)d_in[9];
  const float* lW1 = (const float*)d_in[10];
  const float* lb1 = (const float*)d_in[11];
  const float* lW2 = (const float*)d_in[12];
  const float* lb2 = (const float*)d_in[13];
  const float* tW  = (const float*)d_in[14];
  const float* tb  = (const float*)d_in[15];
  float* out = (float*)d_out;

  char* ws = (char*)d_ws;
  size_t off = 0;
  auto alloc = [&](size_t bytes) -> char* {
    char* p = ws + off;
    off += (bytes + 255) / 256 * 256;
    return p;
  };
  bf16*  xb    = (bf16*) alloc((size_t)8192 * 1024 * 2);        // 16.8 MB
  bf16*  eW1t  = (bf16*) alloc((size_t)20 * 512 * 1024 * 2);    // 21.0 MB [e][512][1024]
  bf16*  eW2t  = (bf16*) alloc((size_t)20 * 256 * 512 * 2);     //  5.2 MB [e][256][512]
  bf16*  Wgt   = (bf16*) alloc((size_t)640 * 1024 * 2);         //  1.3 MB [640][1024]
  float* gbias = (float*)alloc(640 * 4);
  bf16*  gh    = (bf16*) alloc((size_t)8192 * 640 * 2);         // 10.5 MB
  float* wgt   = (float*)alloc((size_t)8192 * 20 * 4);          //  0.7 MB
  float* sPart = (float*)alloc((size_t)20 * 8192 * 4);          //  0.65 MB
  // adaptive expert chunk for h1 reuse (deterministic per ws_size -> capture-safe)
  const size_t per_e = (size_t)8192 * 512 * 2;                  //  8.4 MB / expert
  int G = 20;
  {
    size_t avail = (ws_size > off) ? (ws_size - off) : 0;
    size_t g = avail / per_e;
    if (g < 1) g = 1;
    if (g > 20) g = 20;
    G = (int)g;
  }
  bf16* h1 = (bf16*)alloc(per_e * G);                           // [G][B][512]

  // prep: convert + transpose weights to [N][K] bf16
  k_convert_bf16<<<8192, 256, 0, stream>>>(x, xb, 8192 * 1024);
  k_transpose_to_bf16<<<dim3(16, 32, 20), dim3(32, 8), 0, stream>>>(
      eW1, eW1t, 1024, 512, 1024LL * 512, 512LL * 1024);
  k_transpose_to_bf16<<<dim3(8, 16, 20), dim3(32, 8), 0, stream>>>(
      eW2, eW2t, 512, 256, 512LL * 256, 256LL * 512);
  k_transpose_to_bf16<<<dim3(2, 32, 8), dim3(32, 8), 0, stream>>>(
      gW1, Wgt, 1024, 64, 1024LL * 64, 64LL * 1024);
  k_transpose_to_bf16<<<dim3(2, 32, 1), dim3(32, 8), 0, stream>>>(
      lW1, Wgt + 512 * 1024, 1024, 64, 0, 0);
  k_pack_misc<<<256, 256, 0, stream>>>(gb1, lb1, gbias, Wgt);

  // gating: gh = relu(x @ Wg^T + gbias); then layer-2 + softmax combine -> w[b][20]
  k_gemm_bt<true><<<dim3(5, 64, 1), 256, 0, stream>>>(
      xb, 0, 1024, Wgt, 0, gbias, 0, gh, 0, 640, 1024);
  k_gating2<<<8192, 64, 0, stream>>>(gh, gW2, gb2, lW2, lb2, wgt);

  // expert MLP in chunks of G experts, h1 reused per chunk
  for (int base = 0; base < 20; base += G) {
    int Gc = (20 - base < G) ? (20 - base) : G;
    k_gemm_bt<true><<<dim3(4, 64, Gc), 256, 0, stream>>>(
        xb, 0, 1024, eW1t + (size_t)base * 512 * 1024, 512LL * 1024,
        eb1 + base * 512, 512, h1, 8192LL * 512, 512, 1024);
    k_gemm2_fused<<<dim3(64, Gc), 256, 0, stream>>>(
        h1, eW2t + (size_t)base * 256 * 512,
        eb2 + base * 256, tW, dom, sPart, base);
  }

  // final: logits + sigmoid
  k_final2<<<32, 256, 0, stream>>>(sPart, wgt, dom, tb, out);
}